// Round 10
// baseline (127.193 us; speedup 1.0000x reference)
//
#include <hip/hip_runtime.h>

#define N 8192
#define D 128
#define MARGIN 0.5f
#define FLT_BIG 3.402823466e+38f

typedef __bf16 bf16x8 __attribute__((ext_vector_type(8)));
typedef float f32x4 __attribute__((ext_vector_type(4)));
typedef unsigned short u16x8 __attribute__((ext_vector_type(8)));

__device__ __forceinline__ unsigned short f2bf_rne(float f) {
  unsigned u = __float_as_uint(f);
  u += 0x7FFFu + ((u >> 16) & 1u);  // round-to-nearest-even (inputs finite)
  return (unsigned short)(u >> 16);
}

// xb layout: MFMA-fragment-major over SORTED rows. frag[tile][k][lane][8]:
// tile = p>>4, lane = quad*16 + (p&15); every fragment load is base+lane*16B.
#define FRAG_OFF(tile, k, lane) ((size_t)(tile) * 2048 + (size_t)(k) * 512 + (size_t)(lane) * 8)

// ---------------- K0: per-chunk label histogram + scan -> sort bases ---------
// 1 block x 256. chunk = 16 consecutive rows (512 chunks). Output:
// chunkbase[c][g] = absolute sorted offset of chunk c's first label-g row.
__global__ void k_hist(const int* __restrict__ lab, unsigned* __restrict__ chunkbase,
                       unsigned* __restrict__ cnt8, float* __restrict__ acc,
                       unsigned* __restrict__ ticket) {
  __shared__ unsigned short cnt[512][8];   // 8 KB
  __shared__ unsigned exc[512][8];         // 16 KB
  __shared__ unsigned total[8], labbase[8];
  const int t = threadIdx.x;
  const int lane = t & 63;
  const int w = t >> 6;

#pragma unroll
  for (int cc = 0; cc < 2; ++cc) {  // this thread's two chunks
    const int c = t * 2 + cc;
    unsigned long long cA = 0ull, cB = 0ull;  // 4x16-bit packed counts each
#pragma unroll
    for (int r = 0; r < 16; ++r) {
      const int l = lab[c * 16 + r] & 7;
      if (l < 4) cA += 1ull << (l * 16);
      else       cB += 1ull << ((l - 4) * 16);
    }
#pragma unroll
    for (int g = 0; g < 4; ++g) {
      cnt[c][g]     = (unsigned short)((cA >> (g * 16)) & 0xFFFFu);
      cnt[c][4 + g] = (unsigned short)((cB >> (g * 16)) & 0xFFFFu);
    }
  }
  __syncthreads();

  // per-label prefix over 512 chunks: wave w handles labels w, w+4
  for (int g = w; g < 8; g += 4) {
    unsigned run = 0;
    for (int blk = 0; blk < 8; ++blk) {
      const unsigned v = cnt[blk * 64 + lane][g];
      unsigned x = v;
#pragma unroll
      for (int off = 1; off < 64; off <<= 1) {
        const unsigned y = __shfl_up(x, off, 64);
        if (lane >= off) x += y;
      }
      exc[blk * 64 + lane][g] = run + x - v;
      run += __builtin_amdgcn_readlane(x, 63);
    }
    if (lane == 0) total[g] = run;
  }
  __syncthreads();
  if (t == 0) {
    unsigned run = 0;
#pragma unroll
    for (int g = 0; g < 8; ++g) { labbase[g] = run; run += total[g]; cnt8[g] = total[g]; }
    acc[0] = 0.f; acc[1] = 0.f; ticket[0] = 0u;
  }
  __syncthreads();
#pragma unroll
  for (int e = 0; e < 16; ++e) {  // 4096 entries
    const int idx = t * 16 + e;
    chunkbase[idx] = labbase[idx & 7] + exc[idx >> 3][idx & 7];
  }
}

// ---------------- K1: fp32->bf16 fragment-swizzle into SORTED order ----------
// grid 512 x 256: thread = (row, chunk c): 16 rows/block, 16 chunks/row.
__global__ void k_prep(const float* __restrict__ x, const int* __restrict__ lab,
                       const unsigned* __restrict__ chunkbase,
                       unsigned short* __restrict__ xb, float* __restrict__ sq,
                       int* __restrict__ lab_s, unsigned* __restrict__ posw,
                       unsigned* __restrict__ negw) {
  __shared__ int lab16[16];
  __shared__ unsigned p16[16];
  const int t = threadIdx.x;
  const int rl = t >> 4;  // row within block
  const int c = t & 15;   // chunk within row
  const int row = blockIdx.x * 16 + rl;
  if (c == 0) lab16[rl] = lab[row] & 7;
  __syncthreads();
  if (t < 16) {
    const int lg = lab16[t];
    int rank = 0;
    for (int r2 = 0; r2 < t; ++r2) rank += (lab16[r2] == lg) ? 1 : 0;
    p16[t] = chunkbase[blockIdx.x * 8 + lg] + rank;
  }
  __syncthreads();
  const unsigned p = p16[rl];

  const float4 v0 = ((const float4*)x)[row * 32 + c * 2];
  const float4 v1 = ((const float4*)x)[row * 32 + c * 2 + 1];
  u16x8 o;
  o[0] = f2bf_rne(v0.x); o[1] = f2bf_rne(v0.y);
  o[2] = f2bf_rne(v0.z); o[3] = f2bf_rne(v0.w);
  o[4] = f2bf_rne(v1.x); o[5] = f2bf_rne(v1.y);
  o[6] = f2bf_rne(v1.z); o[7] = f2bf_rne(v1.w);
  *(u16x8*)(xb + FRAG_OFF(p >> 4, c >> 2, ((c & 3) * 16) + (int)(p & 15))) = o;
  float s = v0.x * v0.x + v0.y * v0.y + v0.z * v0.z + v0.w * v0.w +
            v1.x * v1.x + v1.y * v1.y + v1.z * v1.z + v1.w * v1.w;
#pragma unroll
  for (int off = 1; off < 16; off <<= 1) s += __shfl_xor(s, off, 64);
  if (c == 0) {
    sq[p] = s;
    lab_s[p] = lab16[rl];
    posw[p] = 0u;           // max(d2) accumulator
    negw[p] = 0x7F800000u;  // min(d2) accumulator = +inf
  }
}

// ---------------- K2: fused GEMM + mining over SORTED rows -------------------
// grid (32,32) x 256thr. Wave: 64 i x 256 j, no LDS, no barriers, rolled loop.
// Label-sorted rows make most (i-subtile, j-tile) pairs wave-uniformly
// pure-pos (fma+max) or pure-neg (fma+min); only label-boundary tiles take the
// 7-op mixed path. Self-pair lands in pos with d2~0: harmless (hardest positive
// is O(100) for gaussian D=128; singleton classes masked by hist validity).
__global__ __launch_bounds__(256, 3) void k_mine(
    const unsigned short* __restrict__ xb, const float* __restrict__ sq,
    const int* __restrict__ lab_s, unsigned* __restrict__ posw, unsigned* __restrict__ negw) {
  const int t = threadIdx.x;
  const int w = t >> 6;
  const int lane = t & 63;
  const int col = lane & 15;   // MFMA m/n selector
  const int quad = lane >> 4;  // MFMA k-group / C row group
  const int i0 = blockIdx.x * 256 + w * 64;
  const int jbase = blockIdx.y * 256;

  // A fragments resident: 4 i-subtiles x 4 k-steps (coalesced)
  bf16x8 a[4][4];
#pragma unroll
  for (int is = 0; is < 4; ++is)
#pragma unroll
    for (int k = 0; k < 4; ++k)
      a[is][k] = *(const bf16x8*)(xb + FRAG_OFF((i0 >> 4) + is, k, lane));

  // wave-uniform label range per i-subtile (sorted rows)
  int gilo[4], gihi[4];
#pragma unroll
  for (int is = 0; is < 4; ++is) {
    gilo[is] = __builtin_amdgcn_readfirstlane(lab_s[i0 + is * 16]);
    gihi[is] = __builtin_amdgcn_readfirstlane(lab_s[i0 + is * 16 + 15]);
  }
  // per-lane output-row labels, packed 4x8 bits (mixed path only)
  unsigned lab4[4];
#pragma unroll
  for (int is = 0; is < 4; ++is) {
    const int b = i0 + is * 16 + quad * 4;
    lab4[is] = (unsigned)(lab_s[b] & 255) | ((unsigned)(lab_s[b + 1] & 255) << 8) |
               ((unsigned)(lab_s[b + 2] & 255) << 16) | ((unsigned)(lab_s[b + 3] & 255) << 24);
  }

  float pos[4][4], neg[4][4];
#pragma unroll
  for (int is = 0; is < 4; ++is)
#pragma unroll
    for (int r = 0; r < 4; ++r) { pos[is][r] = -FLT_BIG; neg[is][r] = FLT_BIG; }

  const int jt0 = jbase >> 4;
  const float* sqp = sq + jbase + col;
  const int* labp = lab_s + jbase + col;

#pragma unroll 1
  for (int js = 0; js < 16; ++js) {
    const float sqj = sqp[js * 16];
    const int labjv = labp[js * 16] & 7;       // lane's column label
    const int gjlo = __builtin_amdgcn_readfirstlane(labjv);   // col 0
    const int gjhi = __builtin_amdgcn_readlane(labjv, 15);    // col 15
    const unsigned short* g = xb + FRAG_OFF(jt0 + js, 0, lane);
    const bf16x8 b0 = *(const bf16x8*)(g);
    const bf16x8 b1 = *(const bf16x8*)(g + 512);
    const bf16x8 b2 = *(const bf16x8*)(g + 1024);
    const bf16x8 b3 = *(const bf16x8*)(g + 1536);

    f32x4 ac[4];
#pragma unroll
    for (int is = 0; is < 4; ++is) {
      ac[is] = (f32x4){0.f, 0.f, 0.f, 0.f};
      ac[is] = __builtin_amdgcn_mfma_f32_16x16x32_bf16(a[is][0], b0, ac[is], 0, 0, 0);
      ac[is] = __builtin_amdgcn_mfma_f32_16x16x32_bf16(a[is][1], b1, ac[is], 0, 0, 0);
      ac[is] = __builtin_amdgcn_mfma_f32_16x16x32_bf16(a[is][2], b2, ac[is], 0, 0, 0);
      ac[is] = __builtin_amdgcn_mfma_f32_16x16x32_bf16(a[is][3], b3, ac[is], 0, 0, 0);
    }

#pragma unroll
    for (int is = 0; is < 4; ++is) {
      if (gilo[is] == gihi[is] && gilo[is] == gjlo && gjlo == gjhi) {
        // pure positive: whole pair same single label
#pragma unroll
        for (int r = 0; r < 4; ++r)
          pos[is][r] = fmaxf(pos[is][r], fmaf(-2.f, ac[is][r], sqj));
      } else if (gihi[is] < gjlo || gjhi < gilo[is]) {
        // pure negative: disjoint label ranges
#pragma unroll
        for (int r = 0; r < 4; ++r)
          neg[is][r] = fminf(neg[is][r], fmaf(-2.f, ac[is][r], sqj));
      } else {
        // mixed (label boundary): per-element select
        const unsigned diff = lab4[is] ^ ((unsigned)labjv * 0x01010101u);
#pragma unroll
        for (int r = 0; r < 4; ++r) {
          const float m = fmaf(-2.f, ac[is][r], sqj);
          const bool same = ((diff >> (r * 8)) & 255u) == 0u;
          pos[is][r] = fmaxf(pos[is][r], same ? m : -FLT_BIG);
          neg[is][r] = fminf(neg[is][r], same ? FLT_BIG : m);
        }
      }
    }
  }

  // reduce the 16 cols sharing each i-row, add sq_i back, combine via atomics
#pragma unroll
  for (int is = 0; is < 4; ++is)
#pragma unroll
    for (int r = 0; r < 4; ++r) {
      float p = pos[is][r], n = neg[is][r];
#pragma unroll
      for (int off = 1; off < 16; off <<= 1) {
        p = fmaxf(p, __shfl_xor(p, off, 64));
        n = fminf(n, __shfl_xor(n, off, 64));
      }
      if (col == 0) {
        const int i = i0 + is * 16 + quad * 4 + r;
        const float sqi = sq[i];
        atomicMax(posw + i, __float_as_uint(fmaxf(sqi + p, 0.f)));
        atomicMin(negw + i, __float_as_uint(fmaxf(sqi + n, 0.f)));
      }
    }
}

// ---------------- K3: per-row loss + global reduce + finalize (ticketed) -----
// operates entirely in sorted row space (loss is row-order invariant)
__global__ void k_tail(const unsigned* __restrict__ posw, const unsigned* __restrict__ negw,
                       const int* __restrict__ lab_s, const unsigned* __restrict__ hist,
                       float* __restrict__ acc, unsigned* __restrict__ ticket,
                       float* __restrict__ out) {
  __shared__ float ls[4], cs[4];
  const int t = threadIdx.x;
  const int i = blockIdx.x * 256 + t;
  const float pd2 = __uint_as_float(posw[i]);
  const float nd2 = __uint_as_float(negw[i]);
  const unsigned cnt = hist[lab_s[i] & 7];
  const bool valid = (cnt >= 2u) && (cnt < (unsigned)N);
  float loss = 0.f, c = 0.f;
  if (valid) {
    loss = fmaxf(sqrtf(pd2) - sqrtf(fminf(nd2, FLT_BIG)) + MARGIN, 0.f);
    c = 1.f;
  }
#pragma unroll
  for (int off = 1; off < 64; off <<= 1) {
    loss += __shfl_xor(loss, off, 64);
    c += __shfl_xor(c, off, 64);
  }
  const int wv = t >> 6;
  if ((t & 63) == 0) { ls[wv] = loss; cs[wv] = c; }
  __syncthreads();
  if (t == 0) {
    atomicAdd(acc + 0, ls[0] + ls[1] + ls[2] + ls[3]);
    atomicAdd(acc + 1, cs[0] + cs[1] + cs[2] + cs[3]);
    __threadfence();
    const unsigned tk = atomicAdd(ticket, 1u);
    if (tk == 31u) {  // last block: partials fenced-in; read via atomics (coherent)
      const float lsum = atomicAdd(acc + 0, 0.f);
      const float csum = atomicAdd(acc + 1, 0.f);
      out[0] = lsum / fmaxf(csum, 1.f);
    }
  }
}

extern "C" void kernel_launch(void* const* d_in, const int* in_sizes, int n_in,
                              void* d_out, int out_size, void* d_ws, size_t ws_size,
                              hipStream_t stream) {
  const float* x = (const float*)d_in[0];
  const int* lab = (const int*)d_in[1];
  char* ws = (char*)d_ws;
  unsigned short* xb = (unsigned short*)ws;                 // 2 MB bf16 fragment-swizzled (sorted)
  float* sq = (float*)(ws + (size_t)N * D * 2);             // 32 KB (sorted)
  unsigned* posw = (unsigned*)((char*)sq + (size_t)N * 4);  // 32 KB
  unsigned* negw = posw + N;                                // 32 KB
  int* lab_s = (int*)(negw + N);                            // 32 KB (sorted labels)
  unsigned* chunkbase = (unsigned*)(lab_s + N);             // 16 KB (512 x 8)
  unsigned* hist = chunkbase + 512 * 8;                     // 32 B
  unsigned* ticket = hist + 8;                              // 4 B
  float* acc = (float*)(ticket + 1);                        // 8 B
  float* out = (float*)d_out;

  hipLaunchKernelGGL(k_hist, dim3(1), dim3(256), 0, stream, lab, chunkbase, hist, acc, ticket);
  hipLaunchKernelGGL(k_prep, dim3(512), dim3(256), 0, stream, x, lab, chunkbase,
                     xb, sq, lab_s, posw, negw);
  hipLaunchKernelGGL(k_mine, dim3(32, 32), dim3(256), 0, stream, xb, sq, lab_s, posw, negw);
  hipLaunchKernelGGL(k_tail, dim3(32), dim3(256), 0, stream, posw, negw, lab_s, hist,
                     acc, ticket, out);
}

// Round 11
// 110.498 us; speedup vs baseline: 1.1511x; 1.1511x over previous
//
#include <hip/hip_runtime.h>

#define N 8192
#define D 128
#define MARGIN 0.5f
#define FLT_BIG 3.402823466e+38f

typedef __bf16 bf16x8 __attribute__((ext_vector_type(8)));
typedef float f32x4 __attribute__((ext_vector_type(4)));
typedef unsigned short u16x8 __attribute__((ext_vector_type(8)));

__device__ __forceinline__ unsigned short f2bf_rne(float f) {
  unsigned u = __float_as_uint(f);
  u += 0x7FFFu + ((u >> 16) & 1u);  // round-to-nearest-even (inputs finite)
  return (unsigned short)(u >> 16);
}

// xb layout: MFMA-fragment-major. frag[tile][k][lane][8] ushorts, where
// tile = row>>4, lane = quad*16 + (row&15), chunk (4k+quad) = row bytes
// [k*64 + quad*16 .. +16). A and B fragments of the Gram matmul share this
// exact formula, so every fragment load is base + lane*16B (fully coalesced).
#define FRAG_OFF(tile, k, lane) ((size_t)(tile) * 2048 + (size_t)(k) * 512 + (size_t)(lane) * 8)

// ---------------- K1: fp32->bf16 fragment-swizzle + row norms + init ----------
// grid 512 x 256: thread = (row, chunk c): 16 rows/block, 16 chunks/row.
__global__ void k_prep(const float* __restrict__ x, const int* __restrict__ lab,
                       unsigned short* __restrict__ xb, float* __restrict__ sq,
                       unsigned* __restrict__ posw, unsigned* __restrict__ negw,
                       unsigned* __restrict__ hist, float* __restrict__ acc,
                       unsigned* __restrict__ ticket) {
  const int t = threadIdx.x;
  const int row = blockIdx.x * 16 + (t >> 4);
  const int c = t & 15;
  const float4 v0 = ((const float4*)x)[row * 32 + c * 2];
  const float4 v1 = ((const float4*)x)[row * 32 + c * 2 + 1];
  u16x8 o;
  o[0] = f2bf_rne(v0.x); o[1] = f2bf_rne(v0.y);
  o[2] = f2bf_rne(v0.z); o[3] = f2bf_rne(v0.w);
  o[4] = f2bf_rne(v1.x); o[5] = f2bf_rne(v1.y);
  o[6] = f2bf_rne(v1.z); o[7] = f2bf_rne(v1.w);
  // chunk c -> k = c>>2, quad = c&3; lane = quad*16 + (row&15)
  *(u16x8*)(xb + FRAG_OFF(row >> 4, c >> 2, ((c & 3) * 16) + (row & 15))) = o;
  float s = v0.x * v0.x + v0.y * v0.y + v0.z * v0.z + v0.w * v0.w +
            v1.x * v1.x + v1.y * v1.y + v1.z * v1.z + v1.w * v1.w;
#pragma unroll
  for (int off = 1; off < 16; off <<= 1) s += __shfl_xor(s, off, 64);
  if (c == 0) {
    sq[row] = s;
    posw[row] = 0u;           // max(d2) accumulator
    negw[row] = 0x7F800000u;  // min(d2) accumulator = +inf
  }

  if (blockIdx.x == 0) {  // label histogram
    __shared__ unsigned h[8];
    if (t < 8) h[t] = 0u;
    __syncthreads();
    unsigned long long cA = 0ull, cB = 0ull;  // 4x16-bit packed counters each
#pragma unroll
    for (int it = 0; it < 32; ++it) {
      const int l = lab[t + it * 256] & 7;
      if (l < 4) cA += 1ull << (l * 16);
      else       cB += 1ull << ((l - 4) * 16);
    }
#pragma unroll
    for (int off = 1; off < 64; off <<= 1) {
      cA += __shfl_xor(cA, off, 64);
      cB += __shfl_xor(cB, off, 64);
    }
    if ((t & 63) == 0) {
#pragma unroll
      for (int q = 0; q < 4; ++q) {
        atomicAdd(&h[q],     (unsigned)((cA >> (q * 16)) & 0xFFFFu));
        atomicAdd(&h[4 + q], (unsigned)((cB >> (q * 16)) & 0xFFFFu));
      }
    }
    __syncthreads();
    if (t < 8) hist[t] = h[t];
    if (t == 0) { acc[0] = 0.f; acc[1] = 0.f; ticket[0] = 0u; }
  }
}

// ---------------- K2: fused GEMM + hardest-pos/neg mining (no LDS, no barriers) --
// grid (32,32) x 256thr. Each wave: 64 i-rows x 256 j-rows, fully independent.
// (256,2): 256-VGPR budget so the FULL live set (a[4][4]=64 + b=16 + acc=16 +
// pos/neg=32 + addr) stays register-resident. R7/R9's VGPR_Count (48/84) < live
// set proved the allocator was re-loading A-fragments from global every
// iteration ("free spill" of const __restrict data) - THAT was the 40 us
// plateau. 2 blocks/CU resident is enough TLP once the loop is reg-resident.
// Self-term i==j contributes d2~bf16-noise to pos; true hardest positive is
// O(100) here and singleton classes are masked by hist validity -> no diag test.
__global__ __launch_bounds__(256, 2) void k_mine(
    const unsigned short* __restrict__ xb, const float* __restrict__ sq,
    const int* __restrict__ lab, unsigned* __restrict__ posw, unsigned* __restrict__ negw) {
  const int t = threadIdx.x;
  const int w = t >> 6;
  const int lane = t & 63;
  const int col = lane & 15;   // MFMA m/n selector
  const int quad = lane >> 4;  // MFMA k-group / C row group
  const int i0 = blockIdx.x * 256 + w * 64;
  const int jbase = blockIdx.y * 256;

  // A fragments resident: 4 i-subtiles x 4 k-steps (coalesced loads)
  bf16x8 a[4][4];
#pragma unroll
  for (int is = 0; is < 4; ++is)
#pragma unroll
    for (int k = 0; k < 4; ++k)
      a[is][k] = *(const bf16x8*)(xb + FRAG_OFF((i0 >> 4) + is, k, lane));

  // labels for this lane's 4 output rows per subtile, packed 4x8 bits
  unsigned lab4[4];
#pragma unroll
  for (int is = 0; is < 4; ++is) {
    const int b = i0 + is * 16 + quad * 4;
    lab4[is] = (unsigned)(lab[b] & 255) | ((unsigned)(lab[b + 1] & 255) << 8) |
               ((unsigned)(lab[b + 2] & 255) << 16) | ((unsigned)(lab[b + 3] & 255) << 24);
  }

  float pos[4][4], neg[4][4];
#pragma unroll
  for (int is = 0; is < 4; ++is)
#pragma unroll
    for (int r = 0; r < 4; ++r) { pos[is][r] = -FLT_BIG; neg[is][r] = FLT_BIG; }

  const int jt0 = jbase >> 4;
  const float* sqp = sq + jbase + col;
  const int* labp = lab + jbase + col;

#pragma unroll 1
  for (int js = 0; js < 16; ++js) {
    const float sqj = sqp[js * 16];
    const unsigned labj = (unsigned)(labp[js * 16] & 255) * 0x01010101u;
    const unsigned short* g = xb + FRAG_OFF(jt0 + js, 0, lane);
    const bf16x8 b0 = *(const bf16x8*)(g);
    const bf16x8 b1 = *(const bf16x8*)(g + 512);
    const bf16x8 b2 = *(const bf16x8*)(g + 1024);
    const bf16x8 b3 = *(const bf16x8*)(g + 1536);

    f32x4 ac[4];
#pragma unroll
    for (int is = 0; is < 4; ++is) {
      ac[is] = (f32x4){0.f, 0.f, 0.f, 0.f};
      ac[is] = __builtin_amdgcn_mfma_f32_16x16x32_bf16(a[is][0], b0, ac[is], 0, 0, 0);
      ac[is] = __builtin_amdgcn_mfma_f32_16x16x32_bf16(a[is][1], b1, ac[is], 0, 0, 0);
      ac[is] = __builtin_amdgcn_mfma_f32_16x16x32_bf16(a[is][2], b2, ac[is], 0, 0, 0);
      ac[is] = __builtin_amdgcn_mfma_f32_16x16x32_bf16(a[is][3], b3, ac[is], 0, 0, 0);
    }

#pragma unroll
    for (int is = 0; is < 4; ++is) {
      const unsigned diff = lab4[is] ^ labj;  // byte r == 0 iff same label
#pragma unroll
      for (int r = 0; r < 4; ++r) {
        const float m = fmaf(-2.f, ac[is][r], sqj);
        const bool same = ((diff >> (r * 8)) & 255u) == 0u;
        pos[is][r] = fmaxf(pos[is][r], same ? m : -FLT_BIG);
        neg[is][r] = fminf(neg[is][r], same ? FLT_BIG : m);
      }
    }
  }

  // reduce the 16 cols sharing each i-row, add sq_i back, combine via atomics
#pragma unroll
  for (int is = 0; is < 4; ++is)
#pragma unroll
    for (int r = 0; r < 4; ++r) {
      float p = pos[is][r], n = neg[is][r];
#pragma unroll
      for (int off = 1; off < 16; off <<= 1) {
        p = fmaxf(p, __shfl_xor(p, off, 64));
        n = fminf(n, __shfl_xor(n, off, 64));
      }
      if (col == 0) {
        const int i = i0 + is * 16 + quad * 4 + r;
        const float sqi = sq[i];
        atomicMax(posw + i, __float_as_uint(fmaxf(sqi + p, 0.f)));
        atomicMin(negw + i, __float_as_uint(fmaxf(sqi + n, 0.f)));
      }
    }
}

// ---------------- K3: per-row loss + global reduce + finalize (ticketed) -----
__global__ void k_tail(const unsigned* __restrict__ posw, const unsigned* __restrict__ negw,
                       const int* __restrict__ lab, const unsigned* __restrict__ hist,
                       float* __restrict__ acc, unsigned* __restrict__ ticket,
                       float* __restrict__ out) {
  __shared__ float ls[4], cs[4];
  const int t = threadIdx.x;
  const int i = blockIdx.x * 256 + t;
  const float pd2 = __uint_as_float(posw[i]);
  const float nd2 = __uint_as_float(negw[i]);
  const unsigned cnt = hist[lab[i] & 7];
  const bool valid = (cnt >= 2u) && (cnt < (unsigned)N);
  float loss = 0.f, c = 0.f;
  if (valid) {
    loss = fmaxf(sqrtf(pd2) - sqrtf(fminf(nd2, FLT_BIG)) + MARGIN, 0.f);
    c = 1.f;
  }
#pragma unroll
  for (int off = 1; off < 64; off <<= 1) {
    loss += __shfl_xor(loss, off, 64);
    c += __shfl_xor(c, off, 64);
  }
  const int wv = t >> 6;
  if ((t & 63) == 0) { ls[wv] = loss; cs[wv] = c; }
  __syncthreads();
  if (t == 0) {
    atomicAdd(acc + 0, ls[0] + ls[1] + ls[2] + ls[3]);
    atomicAdd(acc + 1, cs[0] + cs[1] + cs[2] + cs[3]);
    __threadfence();
    const unsigned tk = atomicAdd(ticket, 1u);
    if (tk == 31u) {  // last block: partials fenced-in; read via atomics (coherent)
      const float lsum = atomicAdd(acc + 0, 0.f);
      const float csum = atomicAdd(acc + 1, 0.f);
      out[0] = lsum / fmaxf(csum, 1.f);
    }
  }
}

extern "C" void kernel_launch(void* const* d_in, const int* in_sizes, int n_in,
                              void* d_out, int out_size, void* d_ws, size_t ws_size,
                              hipStream_t stream) {
  const float* x = (const float*)d_in[0];
  const int* lab = (const int*)d_in[1];
  char* ws = (char*)d_ws;
  unsigned short* xb = (unsigned short*)ws;                 // 2 MB bf16 fragment-swizzled
  float* sq = (float*)(ws + (size_t)N * D * 2);             // 32 KB
  unsigned* posw = (unsigned*)((char*)sq + (size_t)N * 4);  // 32 KB
  unsigned* negw = posw + N;                                // 32 KB
  unsigned* hist = negw + N;                                // 32 B
  unsigned* ticket = hist + 8;                              // 4 B
  float* acc = (float*)(ticket + 1);                        // 8 B
  float* out = (float*)d_out;

  hipLaunchKernelGGL(k_prep, dim3(512), dim3(256), 0, stream, x, lab, xb, sq,
                     posw, negw, hist, acc, ticket);
  hipLaunchKernelGGL(k_mine, dim3(32, 32), dim3(256), 0, stream, xb, sq, lab, posw, negw);
  hipLaunchKernelGGL(k_tail, dim3(32), dim3(256), 0, stream, posw, negw, lab, hist,
                     acc, ticket, out);
}

// Round 12
// 108.419 us; speedup vs baseline: 1.1732x; 1.0192x over previous
//
#include <hip/hip_runtime.h>

#define N 8192
#define D 128
#define MARGIN 0.5f
#define FLT_BIG 3.402823466e+38f

typedef __bf16 bf16x8 __attribute__((ext_vector_type(8)));
typedef float f32x4 __attribute__((ext_vector_type(4)));
typedef unsigned short u16x8 __attribute__((ext_vector_type(8)));

__device__ __forceinline__ unsigned short f2bf_rne(float f) {
  unsigned u = __float_as_uint(f);
  u += 0x7FFFu + ((u >> 16) & 1u);  // round-to-nearest-even (inputs finite)
  return (unsigned short)(u >> 16);
}

// xb layout: MFMA-fragment-major. frag[tile][k][lane][8] ushorts:
// tile = row>>4, lane = quad*16 + (row&15). A and B fragments of the Gram
// matmul share this formula, so every fragment load is base + lane*16B.
#define FRAG_OFF(tile, k, lane) ((size_t)(tile) * 2048 + (size_t)(k) * 512 + (size_t)(lane) * 8)

// ---------------- K1: fp32->bf16 fragment-swizzle + row norms + init ----------
__global__ void k_prep(const float* __restrict__ x, const int* __restrict__ lab,
                       unsigned short* __restrict__ xb, float* __restrict__ sq,
                       unsigned* __restrict__ posw, unsigned* __restrict__ negw,
                       unsigned* __restrict__ hist, float* __restrict__ acc,
                       unsigned* __restrict__ ticket) {
  const int t = threadIdx.x;
  const int row = blockIdx.x * 16 + (t >> 4);
  const int c = t & 15;
  const float4 v0 = ((const float4*)x)[row * 32 + c * 2];
  const float4 v1 = ((const float4*)x)[row * 32 + c * 2 + 1];
  u16x8 o;
  o[0] = f2bf_rne(v0.x); o[1] = f2bf_rne(v0.y);
  o[2] = f2bf_rne(v0.z); o[3] = f2bf_rne(v0.w);
  o[4] = f2bf_rne(v1.x); o[5] = f2bf_rne(v1.y);
  o[6] = f2bf_rne(v1.z); o[7] = f2bf_rne(v1.w);
  *(u16x8*)(xb + FRAG_OFF(row >> 4, c >> 2, ((c & 3) * 16) + (row & 15))) = o;
  float s = v0.x * v0.x + v0.y * v0.y + v0.z * v0.z + v0.w * v0.w +
            v1.x * v1.x + v1.y * v1.y + v1.z * v1.z + v1.w * v1.w;
#pragma unroll
  for (int off = 1; off < 16; off <<= 1) s += __shfl_xor(s, off, 64);
  if (c == 0) {
    sq[row] = s;
    posw[row] = 0u;           // max(d2) accumulator
    negw[row] = 0x7F800000u;  // min(d2) accumulator = +inf
  }

  if (blockIdx.x == 0) {  // label histogram
    __shared__ unsigned h[8];
    if (t < 8) h[t] = 0u;
    __syncthreads();
    unsigned long long cA = 0ull, cB = 0ull;
#pragma unroll
    for (int it = 0; it < 32; ++it) {
      const int l = lab[t + it * 256] & 7;
      if (l < 4) cA += 1ull << (l * 16);
      else       cB += 1ull << ((l - 4) * 16);
    }
#pragma unroll
    for (int off = 1; off < 64; off <<= 1) {
      cA += __shfl_xor(cA, off, 64);
      cB += __shfl_xor(cB, off, 64);
    }
    if ((t & 63) == 0) {
#pragma unroll
      for (int q = 0; q < 4; ++q) {
        atomicAdd(&h[q],     (unsigned)((cA >> (q * 16)) & 0xFFFFu));
        atomicAdd(&h[4 + q], (unsigned)((cB >> (q * 16)) & 0xFFFFu));
      }
    }
    __syncthreads();
    if (t < 8) hist[t] = h[t];
    if (t == 0) { acc[0] = 0.f; acc[1] = 0.f; ticket[0] = 0u; }
  }
}

// ---------------- K2: fused GEMM + hardest-pos/neg mining --------------------
// grid (32,32) x 256thr. Wave: 64 i x 256 j. No LDS, no barriers.
// KEY (R11 lesson): compiler voluntarily sinks loop-invariant A-fragment loads
// into the loop (VGPR_Count 80 << live set) -> ~20 latency-chained VMEM/iter
// was the 43.7us plateau. Fix: pin A in registers with opaque asm volatile
// (cannot be rematerialized/sunk), and software-pipeline B with two explicit
// register sets (unroll-by-2) so B-loads for the next subtile are in flight
// during this subtile's MFMA+epilogue.
__global__ __launch_bounds__(256, 2) void k_mine(
    const unsigned short* __restrict__ xb, const float* __restrict__ sq,
    const int* __restrict__ lab, unsigned* __restrict__ posw, unsigned* __restrict__ negw) {
  const int t = threadIdx.x;
  const int w = t >> 6;
  const int lane = t & 63;
  const int col = lane & 15;   // MFMA m/n selector
  const int quad = lane >> 4;  // MFMA k-group / C row group
  const int i0 = blockIdx.x * 256 + w * 64;
  const int jbase = blockIdx.y * 256;

  // A fragments: load once, then PIN so they stay register-resident.
  bf16x8 a[4][4];
#pragma unroll
  for (int is = 0; is < 4; ++is)
#pragma unroll
    for (int k = 0; k < 4; ++k)
      a[is][k] = *(const bf16x8*)(xb + FRAG_OFF((i0 >> 4) + is, k, lane));
#pragma unroll
  for (int is = 0; is < 4; ++is)
#pragma unroll
    for (int k = 0; k < 4; ++k)
      asm volatile("" : "+v"(a[is][k]));  // opaque def: no remat, no sink

  // labels for this lane's 4 output rows per subtile, packed 4x8 bits
  unsigned lab4[4];
#pragma unroll
  for (int is = 0; is < 4; ++is) {
    const int b = i0 + is * 16 + quad * 4;
    lab4[is] = (unsigned)(lab[b] & 255) | ((unsigned)(lab[b + 1] & 255) << 8) |
               ((unsigned)(lab[b + 2] & 255) << 16) | ((unsigned)(lab[b + 3] & 255) << 24);
  }

  float pos[4][4], neg[4][4];
#pragma unroll
  for (int is = 0; is < 4; ++is)
#pragma unroll
    for (int r = 0; r < 4; ++r) { pos[is][r] = -FLT_BIG; neg[is][r] = FLT_BIG; }

  const int jt0 = jbase >> 4;
  const float* sqp = sq + jbase + col;
  const int* labp = lab + jbase + col;

  bf16x8 bA0, bA1, bA2, bA3, bB0, bB1, bB2, bB3;
  float sqA, sqB;
  unsigned labA, labB;

#define LOADSET(B0, B1, B2, B3, SQ, LB, JS)                                    \
  {                                                                            \
    const unsigned short* g = xb + FRAG_OFF(jt0 + (JS), 0, lane);              \
    B0 = *(const bf16x8*)(g);                                                  \
    B1 = *(const bf16x8*)(g + 512);                                            \
    B2 = *(const bf16x8*)(g + 1024);                                           \
    B3 = *(const bf16x8*)(g + 1536);                                           \
    SQ = sqp[(JS) * 16];                                                       \
    LB = (unsigned)(labp[(JS) * 16] & 255) * 0x01010101u;                      \
  }

#define COMPUTE(B0, B1, B2, B3, SQ, LB)                                        \
  {                                                                            \
    f32x4 ac[4];                                                               \
    _Pragma("unroll")                                                          \
    for (int is = 0; is < 4; ++is) {                                           \
      ac[is] = (f32x4){0.f, 0.f, 0.f, 0.f};                                    \
      ac[is] = __builtin_amdgcn_mfma_f32_16x16x32_bf16(a[is][0], B0, ac[is], 0, 0, 0); \
      ac[is] = __builtin_amdgcn_mfma_f32_16x16x32_bf16(a[is][1], B1, ac[is], 0, 0, 0); \
      ac[is] = __builtin_amdgcn_mfma_f32_16x16x32_bf16(a[is][2], B2, ac[is], 0, 0, 0); \
      ac[is] = __builtin_amdgcn_mfma_f32_16x16x32_bf16(a[is][3], B3, ac[is], 0, 0, 0); \
    }                                                                          \
    _Pragma("unroll")                                                          \
    for (int is = 0; is < 4; ++is) {                                           \
      const unsigned diff = lab4[is] ^ (LB);                                   \
      _Pragma("unroll")                                                        \
      for (int r = 0; r < 4; ++r) {                                            \
        const float m = fmaf(-2.f, ac[is][r], (SQ));                           \
        const bool same = ((diff >> (r * 8)) & 255u) == 0u;                    \
        pos[is][r] = fmaxf(pos[is][r], same ? m : -FLT_BIG);                   \
        neg[is][r] = fminf(neg[is][r], same ? FLT_BIG : m);                    \
      }                                                                        \
    }                                                                          \
  }

  LOADSET(bA0, bA1, bA2, bA3, sqA, labA, 0);

#pragma unroll 1
  for (int jp = 0; jp < 8; ++jp) {
    // prefetch set B for subtile 2*jp+1, then compute with set A (loads in flight)
    LOADSET(bB0, bB1, bB2, bB3, sqB, labB, jp * 2 + 1);
    COMPUTE(bA0, bA1, bA2, bA3, sqA, labA);
    // prefetch set A for subtile 2*jp+2 (next outer iter), compute with set B
    if (jp < 7) LOADSET(bA0, bA1, bA2, bA3, sqA, labA, jp * 2 + 2);
    COMPUTE(bB0, bB1, bB2, bB3, sqB, labB);
  }
#undef LOADSET
#undef COMPUTE

  // reduce the 16 cols sharing each i-row, add sq_i back, combine via atomics
#pragma unroll
  for (int is = 0; is < 4; ++is)
#pragma unroll
    for (int r = 0; r < 4; ++r) {
      float p = pos[is][r], n = neg[is][r];
#pragma unroll
      for (int off = 1; off < 16; off <<= 1) {
        p = fmaxf(p, __shfl_xor(p, off, 64));
        n = fminf(n, __shfl_xor(n, off, 64));
      }
      if (col == 0) {
        const int i = i0 + is * 16 + quad * 4 + r;
        const float sqi = sq[i];
        atomicMax(posw + i, __float_as_uint(fmaxf(sqi + p, 0.f)));
        atomicMin(negw + i, __float_as_uint(fmaxf(sqi + n, 0.f)));
      }
    }
}

// ---------------- K3: per-row loss + global reduce + finalize (ticketed) -----
__global__ void k_tail(const unsigned* __restrict__ posw, const unsigned* __restrict__ negw,
                       const int* __restrict__ lab, const unsigned* __restrict__ hist,
                       float* __restrict__ acc, unsigned* __restrict__ ticket,
                       float* __restrict__ out) {
  __shared__ float ls[4], cs[4];
  const int t = threadIdx.x;
  const int i = blockIdx.x * 256 + t;
  const float pd2 = __uint_as_float(posw[i]);
  const float nd2 = __uint_as_float(negw[i]);
  const unsigned cnt = hist[lab[i] & 7];
  const bool valid = (cnt >= 2u) && (cnt < (unsigned)N);
  float loss = 0.f, c = 0.f;
  if (valid) {
    loss = fmaxf(sqrtf(pd2) - sqrtf(fminf(nd2, FLT_BIG)) + MARGIN, 0.f);
    c = 1.f;
  }
#pragma unroll
  for (int off = 1; off < 64; off <<= 1) {
    loss += __shfl_xor(loss, off, 64);
    c += __shfl_xor(c, off, 64);
  }
  const int wv = t >> 6;
  if ((t & 63) == 0) { ls[wv] = loss; cs[wv] = c; }
  __syncthreads();
  if (t == 0) {
    atomicAdd(acc + 0, ls[0] + ls[1] + ls[2] + ls[3]);
    atomicAdd(acc + 1, cs[0] + cs[1] + cs[2] + cs[3]);
    __threadfence();
    const unsigned tk = atomicAdd(ticket, 1u);
    if (tk == 31u) {  // last block: partials fenced-in; read via atomics (coherent)
      const float lsum = atomicAdd(acc + 0, 0.f);
      const float csum = atomicAdd(acc + 1, 0.f);
      out[0] = lsum / fmaxf(csum, 1.f);
    }
  }
}

extern "C" void kernel_launch(void* const* d_in, const int* in_sizes, int n_in,
                              void* d_out, int out_size, void* d_ws, size_t ws_size,
                              hipStream_t stream) {
  const float* x = (const float*)d_in[0];
  const int* lab = (const int*)d_in[1];
  char* ws = (char*)d_ws;
  unsigned short* xb = (unsigned short*)ws;                 // 2 MB bf16 fragment-swizzled
  float* sq = (float*)(ws + (size_t)N * D * 2);             // 32 KB
  unsigned* posw = (unsigned*)((char*)sq + (size_t)N * 4);  // 32 KB
  unsigned* negw = posw + N;                                // 32 KB
  unsigned* hist = negw + N;                                // 32 B
  unsigned* ticket = hist + 8;                              // 4 B
  float* acc = (float*)(ticket + 1);                        // 8 B
  float* out = (float*)d_out;

  hipLaunchKernelGGL(k_prep, dim3(512), dim3(256), 0, stream, x, lab, xb, sq,
                     posw, negw, hist, acc, ticket);
  hipLaunchKernelGGL(k_mine, dim3(32, 32), dim3(256), 0, stream, xb, sq, lab, posw, negw);
  hipLaunchKernelGGL(k_tail, dim3(32), dim3(256), 0, stream, posw, negw, lab, hist,
                     acc, ticket, out);
}